// Round 1
// baseline (1822.783 us; speedup 1.0000x reference)
//
#include <hip/hip_runtime.h>
#include <math.h>

// ---------------- problem constants ----------------
#define B_SZ 1024
#define N_   32
#define NUP_ 16
#define M_   4
#define D_   128
#define K_   64
#define F_   32
#define H_   45
#define H_PAD 48
#define L_   3
#define NE   36      // 32 elec j-slots (incl. diagonal, skipped) + 4 nuc
#define LOG2_ 0.69314718055994530942f

__device__ __forceinline__ float ssp(float v) {
    // softplus(v) - log(2), numerically stable
    return fmaxf(v, 0.0f) + log1pf(expf(-fabsf(v))) - LOG2_;
}

// ---------------- prep: transpose small weights into coalesced layouts ----------------
// w1T[l,c][f][64]   (k-padded to 64, zeros beyond 45)
// w2T[l,c][t=0..47][64]  (t zero-padded 45..47)
// gT [l,c][k][128]
// hWT[l][d][64]
__global__ __launch_bounds__(256) void prep_kernel(
    const float* __restrict__ wW1, const float* __restrict__ wW2,
    const float* __restrict__ gW,  const float* __restrict__ hW,
    float* __restrict__ w1T, float* __restrict__ w2T,
    float* __restrict__ gT,  float* __restrict__ hWT)
{
    int blk = blockIdx.x;
    int t = threadIdx.x;
    if (blk < 9) {                       // w1T
        const float* src = wW1 + (size_t)blk * H_ * F_;
        float* dst = w1T + (size_t)blk * F_ * 64;
        for (int idx = t; idx < F_ * 64; idx += 256) {
            int f = idx >> 6, k = idx & 63;
            dst[idx] = (k < H_) ? src[(size_t)k * F_ + f] : 0.0f;
        }
    } else if (blk < 18) {               // w2T
        int b2 = blk - 9;
        const float* src = wW2 + (size_t)b2 * K_ * H_;
        float* dst = w2T + (size_t)b2 * H_PAD * 64;
        for (int idx = t; idx < H_PAD * 64; idx += 256) {
            int tt = idx >> 6, k = idx & 63;
            dst[idx] = (tt < H_) ? src[(size_t)k * H_ + tt] : 0.0f;
        }
    } else if (blk < 27) {               // gT
        int b2 = blk - 18;
        const float* src = gW + (size_t)b2 * D_ * K_;
        float* dst = gT + (size_t)b2 * K_ * D_;
        for (int idx = t; idx < K_ * D_; idx += 256) {
            int k = idx >> 7, d = idx & 127;
            dst[idx] = src[(size_t)d * K_ + k];
        }
    } else {                             // hWT
        int l = blk - 27;
        const float* src = hW + (size_t)l * K_ * D_;
        float* dst = hWT + (size_t)l * D_ * K_;
        for (int idx = t; idx < D_ * K_; idx += 256) {
            int d = idx >> 6, k = idx & 63;
            dst[idx] = src[(size_t)k * D_ + d];
        }
    }
}

// ---------------- h0: layer-0 h is a single broadcast row ----------------
__global__ __launch_bounds__(64) void h0_kernel(
    const float* __restrict__ X, const float* __restrict__ hW,
    const float* __restrict__ hb, float* __restrict__ h0)
{
    int k = threadIdx.x;
    float a = hb[k];
    const float* w = hW + (size_t)k * D_;
    #pragma unroll 8
    for (int dd = 0; dd < D_; ++dd) a += w[dd] * X[dd];
    h0[k] = a;
}

// ---------------- edge kernel: one wave per (b,i) ----------------
// Computes z[b,i,{same,anti,nuc},k] for k=0..63.
__global__ __launch_bounds__(64) void edge_kernel(
    const float* __restrict__ ee, const float* __restrict__ en,
    const float* __restrict__ Y,
    const float* __restrict__ w1T, const float* __restrict__ wb1,
    const float* __restrict__ w2T, const float* __restrict__ wb2,
    const float* __restrict__ h, float* __restrict__ z, int l, int hmode)
{
    int bi = blockIdx.x;
    int b = bi >> 5;
    int i = bi & 31;
    int lane = threadIdx.x;          // 0..63
    bool iup = (i < NUP_);

    __shared__ __attribute__((aligned(16))) float e_s[NE * F_];      // 4608 B
    __shared__ __attribute__((aligned(16))) float hid_s[NE * H_PAD]; // 6912 B

    // ---- stage edges: elec row (contiguous 4 KB) + nuc row ----
    {
        const float4* src = (const float4*)(ee + (size_t)bi * (N_ * F_));
        float4* dst = (float4*)e_s;
        #pragma unroll
        for (int r = 0; r < 4; ++r) dst[lane + 64 * r] = src[lane + 64 * r];
        const float4* srcn = (const float4*)(en + (size_t)bi * (M_ * F_));
        if (lane < 32) dst[256 + lane] = srcn[lane];
    }
    __syncthreads();

    // ---- hidden phase: lane = hidden unit, weights in registers ----
    {
        float w1reg[F_];
        float b1 = 0.0f;
        int c_cur = -1;
        for (int j = 0; j < NE; ++j) {
            int c = (j >= N_) ? 2 : (((j < NUP_) == iup) ? 0 : 1);
            if (c != c_cur) {
                c_cur = c;
                if (lane < H_) {
                    const float* w1p = w1T + (size_t)(l * 3 + c) * F_ * 64 + lane;
                    #pragma unroll
                    for (int f = 0; f < F_; ++f) w1reg[f] = w1p[(size_t)f * 64];
                    b1 = wb1[(size_t)(l * 3 + c) * H_ + lane];
                }
            }
            float hv = 0.0f;
            if (lane < H_) {
                float a = b1;
                #pragma unroll
                for (int f = 0; f < F_; f += 4) {
                    float4 ev = *(const float4*)(e_s + j * F_ + f);
                    a += w1reg[f] * ev.x + w1reg[f+1] * ev.y
                       + w1reg[f+2] * ev.z + w1reg[f+3] * ev.w;
                }
                hv = ssp(a);
            }
            if (lane < H_PAD) hid_s[j * H_PAD + lane] = (lane < H_) ? hv : 0.0f;
        }
    }
    __syncthreads();

    // ---- out phase: lane = k, W2 row (zero-padded to 48) in registers ----
    {
        float w2reg[H_PAD];
        float b2 = 0.0f;
        float zsame = 0.0f, zanti = 0.0f, znuc = 0.0f;
        float hreg0 = (hmode == 0) ? h[lane] : 0.0f;   // layer 0: h broadcast row
        const float* hrow = h + (size_t)b * N_ * K_;

        int c_cur = -1;
        for (int j = 0; j < NE; ++j) {
            if (j == i) continue;
            int c = (j >= N_) ? 2 : (((j < NUP_) == iup) ? 0 : 1);
            if (c != c_cur) {
                c_cur = c;
                const float* w2p = w2T + (size_t)(l * 3 + c) * H_PAD * 64 + lane;
                #pragma unroll
                for (int t = 0; t < H_PAD; ++t) w2reg[t] = w2p[(size_t)t * 64];
                b2 = wb2[(size_t)(l * 3 + c) * K_ + lane];
            }
            float o = b2;
            #pragma unroll
            for (int t = 0; t < H_PAD; t += 4) {
                float4 hv = *(const float4*)(hid_s + j * H_PAD + t);
                o += w2reg[t] * hv.x + w2reg[t+1] * hv.y
                   + w2reg[t+2] * hv.z + w2reg[t+3] * hv.w;
            }
            if (j < N_) {
                float hval = (hmode == 0) ? hreg0 : hrow[(size_t)j * K_ + lane];
                float msg = o * hval;
                if (c == 0) zsame += msg; else zanti += msg;
            } else {
                znuc += o * Y[(size_t)(j - N_) * K_ + lane];
            }
        }
        float* zp = z + (size_t)bi * (3 * K_);
        zp[lane]          = zsame;
        zp[K_ + lane]     = zanti;
        zp[2 * K_ + lane] = znuc;
    }
}

// ---------------- fuse: x += Z @ G^T + biases; h_next = x @ hW^T + hb ----------------
#define TM 32
__global__ __launch_bounds__(256) void fuse_kernel(
    const float* __restrict__ z, const float* __restrict__ gT,
    const float* __restrict__ gb, const float* __restrict__ xin,
    const float* __restrict__ X,
    const float* __restrict__ hWT, const float* __restrict__ hb,
    float* __restrict__ xout, float* __restrict__ hout,
    int l, int first, int compute_h)
{
    int t = threadIdx.x;
    int bi0 = blockIdx.x * TM;
    __shared__ __attribute__((aligned(16))) float Zs[TM * 192];   // 24 KB

    {   // load Z tile (contiguous)
        const float4* src = (const float4*)(z + (size_t)bi0 * 192);
        float4* dst = (float4*)Zs;
        #pragma unroll
        for (int r = 0; r < 6; ++r) dst[t + 256 * r] = src[t + 256 * r];
    }
    __syncthreads();

    int d  = t & 127;
    int rh = t >> 7;                 // 0/1 -> rows rh*16..rh*16+15
    float acc[16];
    #pragma unroll
    for (int r = 0; r < 16; ++r) acc[r] = 0.0f;

    #pragma unroll
    for (int c = 0; c < 3; ++c) {
        const float* gp = gT + (size_t)(l * 3 + c) * K_ * D_ + d;   // gT[.][k][128]
        for (int k = 0; k < K_; k += 4) {
            float g0 = gp[(size_t)(k+0) * D_];
            float g1 = gp[(size_t)(k+1) * D_];
            float g2 = gp[(size_t)(k+2) * D_];
            float g3 = gp[(size_t)(k+3) * D_];
            #pragma unroll
            for (int r = 0; r < 16; ++r) {
                const float4 zv = *(const float4*)(Zs + (rh*16 + r) * 192 + c * K_ + k);
                acc[r] += g0 * zv.x + g1 * zv.y + g2 * zv.z + g3 * zv.w;
            }
        }
    }
    float ub = gb[(size_t)(l*3+0) * D_ + d]
             + gb[(size_t)(l*3+1) * D_ + d]
             + gb[(size_t)(l*3+2) * D_ + d];

    __syncthreads();                 // done reading Zs; reuse as Xs
    float* Xs = Zs;                  // 32*128 = 16 KB fits
    #pragma unroll
    for (int r = 0; r < 16; ++r) {
        int row = rh * 16 + r;
        size_t gi = (size_t)(bi0 + row) * D_ + d;
        float xo = (first ? X[d] : xin[gi]) + ub + acc[r];
        xout[gi] = xo;
        Xs[row * D_ + d] = xo;
    }
    if (!compute_h) return;
    __syncthreads();

    int k  = t & 63;
    int rg = t >> 6;                 // 0..3 -> rows rg*8..rg*8+7
    const float* hwp = hWT + (size_t)(l + 1) * D_ * K_ + k;   // hWT[l+1][d][64]
    float hacc[8];
    #pragma unroll
    for (int r = 0; r < 8; ++r) hacc[r] = 0.0f;
    for (int dd = 0; dd < D_; dd += 4) {
        float w0 = hwp[(size_t)(dd+0) * K_];
        float w1 = hwp[(size_t)(dd+1) * K_];
        float w2 = hwp[(size_t)(dd+2) * K_];
        float w3 = hwp[(size_t)(dd+3) * K_];
        #pragma unroll
        for (int r = 0; r < 8; ++r) {
            const float4 xv = *(const float4*)(Xs + (rg*8 + r) * D_ + dd);
            hacc[r] += w0 * xv.x + w1 * xv.y + w2 * xv.z + w3 * xv.w;
        }
    }
    float hbv = hb[(size_t)(l + 1) * K_ + k];
    #pragma unroll
    for (int r = 0; r < 8; ++r)
        hout[(size_t)(bi0 + rg*8 + r) * K_ + k] = hacc[r] + hbv;
}

// ---------------- launch ----------------
extern "C" void kernel_launch(void* const* d_in, const int* in_sizes, int n_in,
                              void* d_out, int out_size, void* d_ws, size_t ws_size,
                              hipStream_t stream)
{
    const float* ee  = (const float*)d_in[0];
    const float* en  = (const float*)d_in[1];
    const float* X   = (const float*)d_in[2];
    const float* Y   = (const float*)d_in[3];
    const float* wW1 = (const float*)d_in[4];
    const float* wb1 = (const float*)d_in[5];
    const float* wW2 = (const float*)d_in[6];
    const float* wb2 = (const float*)d_in[7];
    const float* hW  = (const float*)d_in[8];
    const float* hb  = (const float*)d_in[9];
    const float* gW  = (const float*)d_in[10];
    const float* gb  = (const float*)d_in[11];
    float* xout = (float*)d_out;

    // workspace layout (floats)
    float* h   = (float*)d_ws;                        // 32768*64
    float* z   = h   + (size_t)32768 * 64;            // 32768*192
    float* h0  = z   + (size_t)32768 * 192;           // 64
    float* w1T = h0  + 64;                            // 9*32*64
    float* w2T = w1T + (size_t)9 * F_ * 64;           // 9*48*64
    float* gT  = w2T + (size_t)9 * H_PAD * 64;        // 9*64*128
    float* hWT = gT  + (size_t)9 * K_ * D_;           // 3*128*64

    prep_kernel<<<30, 256, 0, stream>>>(wW1, wW2, gW, hW, w1T, w2T, gT, hWT);
    h0_kernel<<<1, 64, 0, stream>>>(X, hW, hb, h0);

    // layer 0 (h broadcast row)
    edge_kernel<<<32768, 64, 0, stream>>>(ee, en, Y, w1T, wb1, w2T, wb2, h0, z, 0, 0);
    fuse_kernel<<<1024, 256, 0, stream>>>(z, gT, gb, xout, X, hWT, hb, xout, h, 0, 1, 1);
    // layer 1
    edge_kernel<<<32768, 64, 0, stream>>>(ee, en, Y, w1T, wb1, w2T, wb2, h, z, 1, 1);
    fuse_kernel<<<1024, 256, 0, stream>>>(z, gT, gb, xout, X, hWT, hb, xout, h, 1, 0, 1);
    // layer 2
    edge_kernel<<<32768, 64, 0, stream>>>(ee, en, Y, w1T, wb1, w2T, wb2, h, z, 2, 1);
    fuse_kernel<<<1024, 256, 0, stream>>>(z, gT, gb, xout, X, hWT, hb, xout, h, 2, 0, 0);
}

// Round 2
// 613.608 us; speedup vs baseline: 2.9706x; 2.9706x over previous
//
#include <hip/hip_runtime.h>
#include <math.h>

// ---------------- problem constants ----------------
#define N_   32
#define NUP_ 16
#define M_   4
#define D_   128
#define K_   64
#define F_   32
#define H_   45
#define H_PAD 48
#define L_   3
#define LOG2_ 0.69314718055994530942f

typedef __attribute__((ext_vector_type(8))) short short8;
typedef __attribute__((ext_vector_type(4))) short short4v;
typedef __attribute__((ext_vector_type(4))) float float4v;

__device__ __forceinline__ float ssp(float v) {
    // softplus(v) - log(2), stable, fast intrinsics
    return fmaxf(v, 0.0f) + __logf(1.0f + __expf(-fabsf(v))) - LOG2_;
}

__device__ __forceinline__ unsigned short f2bf(float x) {
    unsigned int u = __float_as_uint(x);
    return (unsigned short)((u + 0x7FFFu + ((u >> 16) & 1u)) >> 16);
}

// ---------------- prep: gT/hWT transposes + MFMA B-fragment weight packs ----------------
// gT [l,c][k][128]          (for fuse kernel)
// hWT[l][d][64]             (for fuse kernel)
// w1B[lc][nt(3)][lane][8]   bf16, B-frag: k=(lane>>4)*8+jj (f), n=nt*16+(lane&15) (hidden)
// w2B[lc][ks(2)][nt(4)][lane][8] bf16: t=ks*32+(lane>>4)*8+jj (hidden), n=nt*16+(lane&15) (kout)
__global__ __launch_bounds__(256) void prep_kernel(
    const float* __restrict__ wW1, const float* __restrict__ wW2,
    const float* __restrict__ gW,  const float* __restrict__ hW,
    float* __restrict__ gT, float* __restrict__ hWT,
    short* __restrict__ w1B, short* __restrict__ w2B)
{
    int blk = blockIdx.x;
    int t = threadIdx.x;
    if (blk < 9) {                        // gT
        const float* src = gW + (size_t)blk * D_ * K_;
        float* dst = gT + (size_t)blk * K_ * D_;
        for (int idx = t; idx < K_ * D_; idx += 256) {
            int k = idx >> 7, d = idx & 127;
            dst[idx] = src[(size_t)d * K_ + k];
        }
    } else if (blk < 12) {                // hWT
        int l = blk - 9;
        const float* src = hW + (size_t)l * K_ * D_;
        float* dst = hWT + (size_t)l * D_ * K_;
        for (int idx = t; idx < D_ * K_; idx += 256) {
            int d = idx >> 6, k = idx & 63;
            dst[idx] = src[(size_t)k * D_ + d];
        }
    } else if (blk < 39) {                // w1B: 27 blocks of 512 elements
        int b2 = blk - 12;
        int lc = b2 / 3, nt = b2 % 3;
        short* dst = w1B + ((size_t)b2) * 512;
        for (int idx = t; idx < 512; idx += 256) {
            int lane = idx >> 3, jj = idx & 7;
            int k = ((lane >> 4) << 3) + jj;        // f index 0..31
            int n = nt * 16 + (lane & 15);          // hidden 0..47
            float v = (n < H_) ? wW1[(size_t)lc * H_ * F_ + (size_t)n * F_ + k] : 0.0f;
            dst[idx] = (short)f2bf(v);
        }
    } else {                              // w2B: 72 blocks of 512
        int b3 = blk - 39;
        int lc = b3 >> 3, rem = b3 & 7, ks = rem >> 2, nt = rem & 3;
        short* dst = w2B + ((size_t)b3) * 512;
        for (int idx = t; idx < 512; idx += 256) {
            int lane = idx >> 3, jj = idx & 7;
            int tt = ks * 32 + ((lane >> 4) << 3) + jj;  // hidden 0..63
            int n = nt * 16 + (lane & 15);               // kout 0..63
            float v = (tt < H_) ? wW2[(size_t)lc * K_ * H_ + (size_t)n * H_ + tt] : 0.0f;
            dst[idx] = (short)f2bf(v);
        }
    }
}

// ---------------- h0: layer-0 h is a single broadcast row ----------------
__global__ __launch_bounds__(64) void h0_kernel(
    const float* __restrict__ X, const float* __restrict__ hW,
    const float* __restrict__ hb, float* __restrict__ h0)
{
    int k = threadIdx.x;
    float a = hb[k];
    const float* w = hW + (size_t)k * D_;
    #pragma unroll 8
    for (int dd = 0; dd < D_; ++dd) a += w[dd] * X[dd];
    h0[k] = a;
}

// ---------------- MFMA edge kernel: 4 waves/WG, one (b,i) per wave ----------------
#define ESTRIDE 40     // bf16 row stride for staged edges
#define WSTRIDE 68     // f32 row stride for h/Y rows
#define HDSTRIDE 72    // bf16 row stride for hidden tile
__global__ __launch_bounds__(256) void edge_kernel(
    const float* __restrict__ ee, const float* __restrict__ en,
    const float* __restrict__ Y,
    const short* __restrict__ w1B, const float* __restrict__ wb1,
    const short* __restrict__ w2B, const float* __restrict__ wb2,
    const float* __restrict__ h, const float* __restrict__ h0,
    float* __restrict__ z, int l, int hmode)
{
    __shared__ float wrow[48 * WSTRIDE];                      // 13056 B
    __shared__ short e_s[4][48 * ESTRIDE];                    // 15360 B
    __shared__ short hd_s[4][16 * HDSTRIDE];                  // 9216 B

    const int tid  = threadIdx.x;
    const int wv   = tid >> 6;
    const int lane = tid & 63;
    const int quad = lane >> 4;
    const int l16  = lane & 15;
    const int b    = blockIdx.x >> 3;
    const int i    = ((blockIdx.x & 7) << 2) + wv;
    const int bi   = (b << 5) + i;

    // ---- stage wrow: h rows 0..31 (or h0 broadcast), Y rows 32..35, zeros 36..47 ----
    {
        int row = tid >> 3;
        int off = (tid & 7) * 8;
        const float* src = hmode ? (h + ((size_t)(b * N_ + row)) * K_ + off) : (h0 + off);
        float4 v0 = *(const float4*)(src);
        float4 v1 = *(const float4*)(src + 4);
        *(float4*)(wrow + row * WSTRIDE + off)     = v0;
        *(float4*)(wrow + row * WSTRIDE + off + 4) = v1;
        if (tid < 32) {
            int r2 = tid >> 3;
            int o2 = (tid & 7) * 8;
            float4 y0 = *(const float4*)(Y + (size_t)r2 * K_ + o2);
            float4 y1 = *(const float4*)(Y + (size_t)r2 * K_ + o2 + 4);
            *(float4*)(wrow + (32 + r2) * WSTRIDE + o2)     = y0;
            *(float4*)(wrow + (32 + r2) * WSTRIDE + o2 + 4) = y1;
        }
        for (int idx = tid; idx < 12 * 64; idx += 256)
            wrow[(36 + (idx >> 6)) * WSTRIDE + (idx & 63)] = 0.0f;
    }

    // ---- stage this wave's edges as bf16 ----
    {
        short* es = e_s[wv];
        int half = lane & 1, row = lane >> 1;                // rows 0..31
        const float* ep = ee + ((size_t)(bi * N_ + row)) * F_ + half * 16;
        float4 a0 = *(const float4*)(ep + 0);
        float4 a1 = *(const float4*)(ep + 4);
        float4 a2 = *(const float4*)(ep + 8);
        float4 a3 = *(const float4*)(ep + 12);
        short8 s0, s1;
        s0[0]=f2bf(a0.x); s0[1]=f2bf(a0.y); s0[2]=f2bf(a0.z); s0[3]=f2bf(a0.w);
        s0[4]=f2bf(a1.x); s0[5]=f2bf(a1.y); s0[6]=f2bf(a1.z); s0[7]=f2bf(a1.w);
        s1[0]=f2bf(a2.x); s1[1]=f2bf(a2.y); s1[2]=f2bf(a2.z); s1[3]=f2bf(a2.w);
        s1[4]=f2bf(a3.x); s1[5]=f2bf(a3.y); s1[6]=f2bf(a3.z); s1[7]=f2bf(a3.w);
        *(short8*)(es + row * ESTRIDE + half * 16)     = s0;
        *(short8*)(es + row * ESTRIDE + half * 16 + 8) = s1;
        if (lane < 8) {
            int r2 = lane >> 1;                              // nuc rows 0..3
            const float* np = en + ((size_t)(bi * M_ + r2)) * F_ + half * 16;
            float4 b0 = *(const float4*)(np + 0);
            float4 b1 = *(const float4*)(np + 4);
            float4 b2 = *(const float4*)(np + 8);
            float4 b3 = *(const float4*)(np + 12);
            short8 t0, t1;
            t0[0]=f2bf(b0.x); t0[1]=f2bf(b0.y); t0[2]=f2bf(b0.z); t0[3]=f2bf(b0.w);
            t0[4]=f2bf(b1.x); t0[5]=f2bf(b1.y); t0[6]=f2bf(b1.z); t0[7]=f2bf(b1.w);
            t1[0]=f2bf(b2.x); t1[1]=f2bf(b2.y); t1[2]=f2bf(b2.z); t1[3]=f2bf(b2.w);
            t1[4]=f2bf(b3.x); t1[5]=f2bf(b3.y); t1[6]=f2bf(b3.z); t1[7]=f2bf(b3.w);
            *(short8*)(es + (32 + r2) * ESTRIDE + half * 16)     = t0;
            *(short8*)(es + (32 + r2) * ESTRIDE + half * 16 + 8) = t1;
        }
        if (lane < 48) {                                     // zero pad rows 36..47
            int r3 = 36 + (lane >> 2), c3 = (lane & 3) * 8;
            short8 zz = {0,0,0,0,0,0,0,0};
            *(short8*)(es + r3 * ESTRIDE + c3) = zz;
        }
        // zero hd cols 48..63 (never rewritten)
        short* hd = hd_s[wv];
        {
            int r4 = lane >> 2, c4 = 48 + (lane & 3) * 4;
            short4v z4 = {0,0,0,0};
            *(short4v*)(hd + r4 * HDSTRIDE + c4) = z4;
        }
    }
    __syncthreads();

    const int cA = (i < NUP_) ? 0 : 1;
    const short* es = e_s[wv];
    short* hd = hd_s[wv];

    #pragma unroll
    for (int t = 0; t < 3; ++t) {
        const int c  = (t == 2) ? 2 : ((t == 0) ? cA : 1 - cA);
        const int lc = l * 3 + c;

        // ---- stage 1: E-tile @ W1^T  (one K-step) ----
        short8 a1 = *(const short8*)(es + (t * 16 + l16) * ESTRIDE + quad * 8);
        float4v acc1[3];
        #pragma unroll
        for (int nt = 0; nt < 3; ++nt) {
            int col = nt * 16 + l16;
            float b1c = (col < H_) ? wb1[(size_t)lc * H_ + col] : 0.0f;
            acc1[nt] = (float4v){b1c, b1c, b1c, b1c};
            short8 bf = *(const short8*)(w1B + (((size_t)lc * 3 + nt) << 9) + (lane << 3));
            acc1[nt] = __builtin_amdgcn_mfma_f32_16x16x32_bf16(a1, bf, acc1[nt], 0, 0, 0);
        }
        // ---- ssp + write hidden tile (bf16, C-layout -> LDS) ----
        #pragma unroll
        for (int nt = 0; nt < 3; ++nt) {
            int col = nt * 16 + l16;
            #pragma unroll
            for (int r = 0; r < 4; ++r) {
                float v = ssp(acc1[nt][r]);
                if (col >= H_) v = 0.0f;
                hd[(quad * 4 + r) * HDSTRIDE + col] = (short)f2bf(v);
            }
        }

        // ---- stage 2: H-tile @ W2^T  (two K-steps) ----
        float4v acc2[4];
        #pragma unroll
        for (int nt = 0; nt < 4; ++nt) {
            float b2c = wb2[(size_t)lc * K_ + nt * 16 + l16];
            acc2[nt] = (float4v){b2c, b2c, b2c, b2c};
        }
        #pragma unroll
        for (int ks = 0; ks < 2; ++ks) {
            short8 a2 = *(const short8*)(hd + l16 * HDSTRIDE + ks * 32 + quad * 8);
            #pragma unroll
            for (int nt = 0; nt < 4; ++nt) {
                short8 bf = *(const short8*)(w2B + ((((size_t)lc * 2 + ks) * 4 + nt) << 9) + (lane << 3));
                acc2[nt] = __builtin_amdgcn_mfma_f32_16x16x32_bf16(a2, bf, acc2[nt], 0, 0, 0);
            }
        }

        // ---- epilogue: msg * h(row,col), sum over rows ----
        float p0 = 0.f, p1 = 0.f, p2 = 0.f, p3 = 0.f;
        #pragma unroll
        for (int r = 0; r < 4; ++r) {
            int jrow = t * 16 + quad * 4 + r;
            const float* wr = wrow + jrow * WSTRIDE + l16;
            float w0 = wr[0], w1 = wr[16], w2 = wr[32], w3 = wr[48];
            if (t < 2 && jrow == i) { w0 = 0.f; w1 = 0.f; w2 = 0.f; w3 = 0.f; }
            p0 += acc2[0][r] * w0;
            p1 += acc2[1][r] * w1;
            p2 += acc2[2][r] * w2;
            p3 += acc2[3][r] * w3;
        }
        p0 += __shfl_xor(p0, 16); p0 += __shfl_xor(p0, 32);
        p1 += __shfl_xor(p1, 16); p1 += __shfl_xor(p1, 32);
        p2 += __shfl_xor(p2, 16); p2 += __shfl_xor(p2, 32);
        p3 += __shfl_xor(p3, 16); p3 += __shfl_xor(p3, 32);

        float v = p0;
        v = (quad == 1) ? p1 : v;
        v = (quad == 2) ? p2 : v;
        v = (quad == 3) ? p3 : v;
        z[(size_t)bi * 192 + c * 64 + lane] = v;   // slot == channel
    }
}

// ---------------- fuse: x += Z @ G^T + biases; h_next = x @ hW^T + hb ----------------
#define TM 32
__global__ __launch_bounds__(256) void fuse_kernel(
    const float* __restrict__ z, const float* __restrict__ gT,
    const float* __restrict__ gb, const float* __restrict__ xin,
    const float* __restrict__ X,
    const float* __restrict__ hWT, const float* __restrict__ hb,
    float* __restrict__ xout, float* __restrict__ hout,
    int l, int first, int compute_h)
{
    int t = threadIdx.x;
    int bi0 = blockIdx.x * TM;
    __shared__ __attribute__((aligned(16))) float Zs[TM * 192];   // 24 KB

    {   // load Z tile (contiguous)
        const float4* src = (const float4*)(z + (size_t)bi0 * 192);
        float4* dst = (float4*)Zs;
        #pragma unroll
        for (int r = 0; r < 6; ++r) dst[t + 256 * r] = src[t + 256 * r];
    }
    __syncthreads();

    int d  = t & 127;
    int rh = t >> 7;
    float acc[16];
    #pragma unroll
    for (int r = 0; r < 16; ++r) acc[r] = 0.0f;

    #pragma unroll
    for (int c = 0; c < 3; ++c) {
        const float* gp = gT + (size_t)(l * 3 + c) * K_ * D_ + d;
        for (int k = 0; k < K_; k += 4) {
            float g0 = gp[(size_t)(k+0) * D_];
            float g1 = gp[(size_t)(k+1) * D_];
            float g2 = gp[(size_t)(k+2) * D_];
            float g3 = gp[(size_t)(k+3) * D_];
            #pragma unroll
            for (int r = 0; r < 16; ++r) {
                const float4 zv = *(const float4*)(Zs + (rh*16 + r) * 192 + c * K_ + k);
                acc[r] += g0 * zv.x + g1 * zv.y + g2 * zv.z + g3 * zv.w;
            }
        }
    }
    float ub = gb[(size_t)(l*3+0) * D_ + d]
             + gb[(size_t)(l*3+1) * D_ + d]
             + gb[(size_t)(l*3+2) * D_ + d];

    __syncthreads();
    float* Xs = Zs;
    #pragma unroll
    for (int r = 0; r < 16; ++r) {
        int row = rh * 16 + r;
        size_t gi = (size_t)(bi0 + row) * D_ + d;
        float xo = (first ? X[d] : xin[gi]) + ub + acc[r];
        xout[gi] = xo;
        Xs[row * D_ + d] = xo;
    }
    if (!compute_h) return;
    __syncthreads();

    int k  = t & 63;
    int rg = t >> 6;
    const float* hwp = hWT + (size_t)(l + 1) * D_ * K_ + k;
    float hacc[8];
    #pragma unroll
    for (int r = 0; r < 8; ++r) hacc[r] = 0.0f;
    for (int dd = 0; dd < D_; dd += 4) {
        float w0 = hwp[(size_t)(dd+0) * K_];
        float w1 = hwp[(size_t)(dd+1) * K_];
        float w2 = hwp[(size_t)(dd+2) * K_];
        float w3 = hwp[(size_t)(dd+3) * K_];
        #pragma unroll
        for (int r = 0; r < 8; ++r) {
            const float4 xv = *(const float4*)(Xs + (rg*8 + r) * D_ + dd);
            hacc[r] += w0 * xv.x + w1 * xv.y + w2 * xv.z + w3 * xv.w;
        }
    }
    float hbv = hb[(size_t)(l + 1) * K_ + k];
    #pragma unroll
    for (int r = 0; r < 8; ++r)
        hout[(size_t)(bi0 + rg*8 + r) * K_ + k] = hacc[r] + hbv;
}

// ---------------- launch ----------------
extern "C" void kernel_launch(void* const* d_in, const int* in_sizes, int n_in,
                              void* d_out, int out_size, void* d_ws, size_t ws_size,
                              hipStream_t stream)
{
    const float* ee  = (const float*)d_in[0];
    const float* en  = (const float*)d_in[1];
    const float* X   = (const float*)d_in[2];
    const float* Y   = (const float*)d_in[3];
    const float* wW1 = (const float*)d_in[4];
    const float* wb1 = (const float*)d_in[5];
    const float* wW2 = (const float*)d_in[6];
    const float* wb2 = (const float*)d_in[7];
    const float* hW  = (const float*)d_in[8];
    const float* hb  = (const float*)d_in[9];
    const float* gW  = (const float*)d_in[10];
    const float* gb  = (const float*)d_in[11];
    float* xout = (float*)d_out;

    // workspace layout (floats / shorts)
    float* h   = (float*)d_ws;                        // 32768*64
    float* zb  = h   + (size_t)32768 * 64;            // 32768*192
    float* h0  = zb  + (size_t)32768 * 192;           // 64
    float* gT  = h0  + 64;                            // 9*64*128
    float* hWT = gT  + (size_t)9 * K_ * D_;           // 3*128*64
    short* w1B = (short*)(hWT + (size_t)3 * D_ * K_); // 9*3*512 shorts
    short* w2B = w1B + (size_t)27 * 512;              // 9*8*512 shorts

    prep_kernel<<<111, 256, 0, stream>>>(wW1, wW2, gW, hW, gT, hWT, w1B, w2B);
    h0_kernel<<<1, 64, 0, stream>>>(X, hW, hb, h0);

    // layer 0 (h broadcast row)
    edge_kernel<<<8192, 256, 0, stream>>>(ee, en, Y, w1B, wb1, w2B, wb2, h, h0, zb, 0, 0);
    fuse_kernel<<<1024, 256, 0, stream>>>(zb, gT, gb, xout, X, hWT, hb, xout, h, 0, 1, 1);
    // layer 1
    edge_kernel<<<8192, 256, 0, stream>>>(ee, en, Y, w1B, wb1, w2B, wb2, h, h0, zb, 1, 1);
    fuse_kernel<<<1024, 256, 0, stream>>>(zb, gT, gb, xout, X, hWT, hb, xout, h, 1, 0, 1);
    // layer 2
    edge_kernel<<<8192, 256, 0, stream>>>(ee, en, Y, w1B, wb1, w2B, wb2, h, h0, zb, 2, 2);
    fuse_kernel<<<1024, 256, 0, stream>>>(zb, gT, gb, xout, X, hWT, hb, xout, h, 2, 0, 0);
}

// Round 3
// 438.895 us; speedup vs baseline: 4.1531x; 1.3981x over previous
//
#include <hip/hip_runtime.h>
#include <math.h>

// ---------------- problem constants ----------------
#define N_   32
#define NUP_ 16
#define M_   4
#define D_   128
#define K_   64
#define F_   32
#define H_   45
#define L_   3
#define LOG2_ 0.69314718055994530942f

typedef __attribute__((ext_vector_type(8))) short short8;
typedef __attribute__((ext_vector_type(4))) float float4v;

__device__ __forceinline__ float ssp(float v) {
    // softplus(v) - log(2): ssp(0) == 0 exactly (log2(2)=1 path)
    return __logf(1.0f + __expf(v)) - LOG2_;
}

__device__ __forceinline__ unsigned short f2bf(float x) {   // RTNE, prep only
    unsigned int u = __float_as_uint(x);
    return (unsigned short)((u + 0x7FFFu + ((u >> 16) & 1u)) >> 16);
}

// pack two floats -> bf16x2 (round-half-up via +0x8000 carry)
__device__ __forceinline__ unsigned int pkbf(float x, float y) {
    return __builtin_amdgcn_perm(__float_as_uint(y) + 0x8000u,
                                 __float_as_uint(x) + 0x8000u, 0x07060302u);
}

// ---------------- prep: pack all weights into MFMA B-fragment order ----------------
// w1B[lc][nt:3][512]   B-frag: k=(lane>>4)*8+jj (f), n=nt*16+(lane&15) (hidden, id map)
// w2B[lc][ks:2][nt:4][512]  k=p (hidden position), n=kout. pos p: u=(p&3)*16+(p>>2) if p&3<3;
//                            p==3 -> bias row (pairs with hd[row][3]=1.0); else 0
// gB [l][ks:6][nt:8][512]   k=c*64+kk, n=d
// hB [li:2][ks:4][nt2:4][512] k=p, d=(p&7)*16+(p>>3), n=kout   (hW layers 1,2)
// gbs[l][128] = sum_c gb[l][c][:]
__global__ __launch_bounds__(256) void prep_kernel(
    const float* __restrict__ wW1, const float* __restrict__ wb2_unused,
    const float* __restrict__ wW2, const float* __restrict__ wb2,
    const float* __restrict__ gW,  const float* __restrict__ hW,
    const float* __restrict__ gb,
    short* __restrict__ w1B, short* __restrict__ w2B,
    short* __restrict__ gB,  short* __restrict__ hB, float* __restrict__ gbs)
{
    int blk = blockIdx.x;
    int t = threadIdx.x;
    if (blk < 27) {                       // w1B
        int lc = blk / 3, nt = blk % 3;
        short* dst = w1B + (size_t)blk * 512;
        for (int idx = t; idx < 512; idx += 256) {
            int lane = idx >> 3, jj = idx & 7;
            int k = ((lane >> 4) << 3) + jj;
            int n = nt * 16 + (lane & 15);
            float v = (n < H_) ? wW1[((size_t)lc * H_ + n) * F_ + k] : 0.0f;
            dst[idx] = (short)f2bf(v);
        }
    } else if (blk < 99) {                // w2B
        int b3 = blk - 27;
        int lc = b3 >> 3, rem = b3 & 7, ks = rem >> 2, nt = rem & 3;
        short* dst = w2B + (size_t)b3 * 512;
        for (int idx = t; idx < 512; idx += 256) {
            int lane = idx >> 3, jj = idx & 7;
            int p = ks * 32 + ((lane >> 4) << 3) + jj;
            int n = nt * 16 + (lane & 15);
            float v;
            if (p == 3) v = wb2[(size_t)lc * K_ + n];
            else if ((p & 3) < 3) {
                int u = (p & 3) * 16 + (p >> 2);
                v = (u < H_) ? wW2[((size_t)lc * K_ + n) * H_ + u] : 0.0f;
            } else v = 0.0f;
            dst[idx] = (short)f2bf(v);
        }
    } else if (blk < 243) {               // gB
        int g = blk - 99;
        int l = g / 48, rem = g % 48;     // rem = ks*8+nt
        short* dst = gB + (size_t)g * 512;
        for (int idx = t; idx < 512; idx += 256) {
            int lane = idx >> 3, jj = idx & 7;
            int k = (rem >> 3) * 32 + ((lane >> 4) << 3) + jj;  // 0..191
            int c = k >> 6, kk = k & 63;
            int n = ((rem & 7) * 16) + (lane & 15);
            dst[idx] = (short)f2bf(gW[(((size_t)l * 3 + c) * D_ + n) * K_ + kk]);
        }
    } else if (blk < 275) {               // hB
        int hh = blk - 243;
        int li = hh >> 4, rem = hh & 15;  // rem = ks*4+nt2
        short* dst = hB + (size_t)hh * 512;
        for (int idx = t; idx < 512; idx += 256) {
            int lane = idx >> 3, jj = idx & 7;
            int p = (rem >> 2) * 32 + ((lane >> 4) << 3) + jj;  // 0..127
            int d = (p & 7) * 16 + (p >> 3);
            int n = ((rem & 3) * 16) + (lane & 15);
            dst[idx] = (short)f2bf(hW[(((size_t)(li + 1)) * K_ + n) * D_ + d]);
        }
    } else {                              // gbs
        for (int idx = t; idx < 384; idx += 256) {
            int l = idx >> 7, d = idx & 127;
            gbs[idx] = gb[((size_t)l * 3 + 0) * D_ + d]
                     + gb[((size_t)l * 3 + 1) * D_ + d]
                     + gb[((size_t)l * 3 + 2) * D_ + d];
        }
    }
}

// ---------------- h0: layer-0 h is a single broadcast row ----------------
__global__ __launch_bounds__(64) void h0_kernel(
    const float* __restrict__ X, const float* __restrict__ hW,
    const float* __restrict__ hb, float* __restrict__ h0)
{
    int k = threadIdx.x;
    float a = hb[k];
    const float* w = hW + (size_t)k * D_;
    #pragma unroll 8
    for (int dd = 0; dd < D_; ++dd) a += w[dd] * X[dd];
    h0[k] = a;
}

// ---------------- MFMA edge kernel: 4 waves/WG, one (b,i) per wave ----------------
#define WSTRIDE 68     // f32 words per wrow row
#define HDS 72         // shorts per hd row (16B-aligned stride, bank-spread)
__global__ __launch_bounds__(256, 6) void edge_kernel(
    const float* __restrict__ ee, const float* __restrict__ en,
    const float* __restrict__ Y,
    const short* __restrict__ w1B, const float* __restrict__ wb1,
    const short* __restrict__ w2B,
    const float* __restrict__ h, const float* __restrict__ h0,
    unsigned short* __restrict__ zb, int l, int hmode)
{
    __shared__ float wrow[36 * WSTRIDE];          // 9792 B (h rows 0..31, Y rows 32..35)
    __shared__ short hd_s[4][16 * HDS];           // 9216 B

    const int tid  = threadIdx.x;
    const int wv   = tid >> 6;
    const int lane = tid & 63;
    const int quad = lane >> 4;
    const int l16  = lane & 15;
    const int b    = blockIdx.x >> 3;
    const int i    = ((blockIdx.x & 7) << 2) + wv;
    const int bi   = (b << 5) + i;

    // ---- stage wrow cooperatively ----
    {
        int row = tid >> 3;
        int col = (tid & 7) * 8;
        const float* src = hmode ? (h + ((size_t)(b * N_ + row)) * K_ + col) : (h0 + col);
        float4 v0 = *(const float4*)(src);
        float4 v1 = *(const float4*)(src + 4);
        *(float4*)(wrow + row * WSTRIDE + col)     = v0;
        *(float4*)(wrow + row * WSTRIDE + col + 4) = v1;
        if (tid < 32) {
            int r2 = tid >> 3, o2 = (tid & 7) * 8;
            float4 y0 = *(const float4*)(Y + (size_t)r2 * K_ + o2);
            float4 y1 = *(const float4*)(Y + (size_t)r2 * K_ + o2 + 4);
            *(float4*)(wrow + (32 + r2) * WSTRIDE + o2)     = y0;
            *(float4*)(wrow + (32 + r2) * WSTRIDE + o2 + 4) = y1;
        }
    }
    __syncthreads();

    const int cA = (i < NUP_) ? 0 : 1;
    short* hd = hd_s[wv];
    const unsigned int cpad = (l16 == 0) ? 0x3F808000u : 0u;  // 1.0 bf16 in bias slot

    #pragma unroll
    for (int t = 0; t < 3; ++t) {
        const int c  = (t == 2) ? 2 : ((t == 0) ? cA : 1 - cA);
        const int lc = l * 3 + c;

        // ---- A-frag: 8 consecutive f of this lane's edge row, straight from global ----
        float4 fa = {0.f, 0.f, 0.f, 0.f}, fb = {0.f, 0.f, 0.f, 0.f};
        if (t < 2) {
            const float* ep = ee + (((size_t)bi * N_) + t * 16 + l16) * F_ + quad * 8;
            fa = *(const float4*)(ep);
            fb = *(const float4*)(ep + 4);
        } else if (l16 < M_) {
            const float* np = en + (((size_t)bi * M_) + l16) * F_ + quad * 8;
            fa = *(const float4*)(np);
            fb = *(const float4*)(np + 4);
        }
        union { short8 s; unsigned int u[4]; } A;
        A.u[0] = pkbf(fa.x, fa.y); A.u[1] = pkbf(fa.z, fa.w);
        A.u[2] = pkbf(fb.x, fb.y); A.u[3] = pkbf(fb.z, fb.w);

        // ---- stage 1: one K-step, 3 column tiles ----
        float4v acc1[3];
        #pragma unroll
        for (int nt = 0; nt < 3; ++nt) {
            int col = nt * 16 + l16;
            float b1c = (col < H_) ? wb1[(size_t)lc * H_ + col] : 0.0f;
            acc1[nt] = (float4v){b1c, b1c, b1c, b1c};
            short8 bf = *(const short8*)(w1B + (((size_t)lc * 3 + nt) << 9) + (lane << 3));
            acc1[nt] = __builtin_amdgcn_mfma_f32_16x16x32_bf16(A.s, bf, acc1[nt], 0, 0, 0);
        }

        // ---- ssp + packed b64 hidden write (pos = 4*l16 + nt, junk slot = bias 1.0) ----
        #pragma unroll
        for (int r = 0; r < 4; ++r) {
            float s0 = ssp(acc1[0][r]);
            float s1 = ssp(acc1[1][r]);
            float s2 = ssp(acc1[2][r]);
            unsigned int lo = pkbf(s0, s1);
            unsigned int hi = __builtin_amdgcn_perm(cpad, __float_as_uint(s2) + 0x8000u, 0x07060302u);
            uint2 pr; pr.x = lo; pr.y = hi;
            *(uint2*)(hd + (quad * 4 + r) * HDS + 4 * l16) = pr;
        }

        // ---- stage 2: two K-steps, bias via k=3 slot ----
        float4v acc2[4];
        #pragma unroll
        for (int nt = 0; nt < 4; ++nt) acc2[nt] = (float4v){0.f, 0.f, 0.f, 0.f};
        #pragma unroll
        for (int ks = 0; ks < 2; ++ks) {
            short8 a2 = *(const short8*)(hd + l16 * HDS + ks * 32 + quad * 8);
            #pragma unroll
            for (int nt = 0; nt < 4; ++nt) {
                short8 bf = *(const short8*)(w2B + ((((size_t)lc * 2 + ks) * 4 + nt) << 9) + (lane << 3));
                acc2[nt] = __builtin_amdgcn_mfma_f32_16x16x32_bf16(a2, bf, acc2[nt], 0, 0, 0);
            }
        }

        // ---- epilogue: msg * h(j,k), sum over rows ----
        float p0 = 0.f, p1 = 0.f, p2 = 0.f, p3 = 0.f;
        #pragma unroll
        for (int r = 0; r < 4; ++r) {
            int jrow = t * 16 + quad * 4 + r;
            const float* wr = wrow + jrow * WSTRIDE + l16;
            float w0 = wr[0], w1 = wr[16], w2 = wr[32], w3 = wr[48];
            bool live = (t == 2) ? (jrow < 36) : (jrow != i);
            if (!live) { w0 = 0.f; w1 = 0.f; w2 = 0.f; w3 = 0.f; }
            p0 += acc2[0][r] * w0;
            p1 += acc2[1][r] * w1;
            p2 += acc2[2][r] * w2;
            p3 += acc2[3][r] * w3;
        }
        p0 += __shfl_xor(p0, 16); p0 += __shfl_xor(p0, 32);
        p1 += __shfl_xor(p1, 16); p1 += __shfl_xor(p1, 32);
        p2 += __shfl_xor(p2, 16); p2 += __shfl_xor(p2, 32);
        p3 += __shfl_xor(p3, 16); p3 += __shfl_xor(p3, 32);

        float v = p0;
        v = (quad == 1) ? p1 : v;
        v = (quad == 2) ? p2 : v;
        v = (quad == 3) ? p3 : v;
        zb[(size_t)bi * 192 + c * 64 + lane] =
            (unsigned short)((__float_as_uint(v) + 0x8000u) >> 16);
    }
}

// ---------------- MFMA fuse: x += Z@Gcat^T + gbs; h_next = x@hW^T + hb ----------------
#define HXS 136   // shorts per hx row
__global__ __launch_bounds__(256) void fuse_kernel(
    const unsigned short* __restrict__ zb, const short* __restrict__ gB,
    const float* __restrict__ gbs, const float* __restrict__ X,
    const short* __restrict__ hB, const float* __restrict__ hb,
    float* __restrict__ xout, float* __restrict__ hout,
    int l, int first, int compute_h)
{
    __shared__ short hx_s[4][16 * HXS];    // 17408 B

    const int tid  = threadIdx.x;
    const int wv   = tid >> 6;
    const int lane = tid & 63;
    const int quad = lane >> 4;
    const int l16  = lane & 15;
    const int bi0  = (blockIdx.x * 4 + wv) * 16;

    // ---- Z @ Gcat^T : 6 K-steps x 8 column tiles ----
    float4v ax[8];
    #pragma unroll
    for (int nt = 0; nt < 8; ++nt) ax[nt] = (float4v){0.f, 0.f, 0.f, 0.f};
    const short* gb_ = gB + (size_t)l * 48 * 512;
    const short* zrow = (const short*)zb + ((size_t)(bi0 + l16)) * 192;
    #pragma unroll
    for (int ks = 0; ks < 6; ++ks) {
        short8 az = *(const short8*)(zrow + ks * 32 + quad * 8);
        #pragma unroll
        for (int nt = 0; nt < 8; ++nt) {
            short8 bf = *(const short8*)(gb_ + (((size_t)ks * 8 + nt) << 9) + (lane << 3));
            ax[nt] = __builtin_amdgcn_mfma_f32_16x16x32_bf16(az, bf, ax[nt], 0, 0, 0);
        }
    }

    // ---- epilogue: residual + biases, store x, pack bf16 rows for h-GEMM ----
    float gv[8], xb[8];
    #pragma unroll
    for (int nt = 0; nt < 8; ++nt) {
        gv[nt] = gbs[(size_t)l * D_ + nt * 16 + l16];
        if (first) xb[nt] = X[nt * 16 + l16];
    }
    short* hx = hx_s[wv];
    #pragma unroll
    for (int r = 0; r < 4; ++r) {
        int row = quad * 4 + r;
        size_t gi = ((size_t)(bi0 + row)) * D_ + l16;
        float xv[8];
        #pragma unroll
        for (int nt = 0; nt < 8; ++nt) {
            float xo = (first ? xb[nt] : xout[gi + nt * 16]) + gv[nt] + ax[nt][r];
            xout[gi + nt * 16] = xo;
            xv[nt] = xo;
        }
        if (compute_h) {
            union { short8 s; unsigned int u[4]; } P;
            P.u[0] = pkbf(xv[0], xv[1]); P.u[1] = pkbf(xv[2], xv[3]);
            P.u[2] = pkbf(xv[4], xv[5]); P.u[3] = pkbf(xv[6], xv[7]);
            *(short8*)(hx + row * HXS + 8 * l16) = P.s;
        }
    }
    if (!compute_h) return;

    // ---- h_next = x @ hW^T : 4 K-steps x 4 column tiles ----
    float4v ah[4];
    #pragma unroll
    for (int nt = 0; nt < 4; ++nt) ah[nt] = (float4v){0.f, 0.f, 0.f, 0.f};
    const short* hb_ = hB + (size_t)l * 16 * 512;
    #pragma unroll
    for (int ks = 0; ks < 4; ++ks) {
        short8 a = *(const short8*)(hx + l16 * HXS + ks * 32 + quad * 8);
        #pragma unroll
        for (int nt = 0; nt < 4; ++nt) {
            short8 bf = *(const short8*)(hb_ + (((size_t)ks * 4 + nt) << 9) + (lane << 3));
            ah[nt] = __builtin_amdgcn_mfma_f32_16x16x32_bf16(a, bf, ah[nt], 0, 0, 0);
        }
    }
    float hbv[4];
    #pragma unroll
    for (int nt = 0; nt < 4; ++nt) hbv[nt] = hb[((size_t)(l + 1)) * K_ + nt * 16 + l16];
    #pragma unroll
    for (int nt = 0; nt < 4; ++nt)
        #pragma unroll
        for (int r = 0; r < 4; ++r)
            hout[((size_t)(bi0 + quad * 4 + r)) * K_ + nt * 16 + l16] = ah[nt][r] + hbv[nt];
}

// ---------------- launch ----------------
extern "C" void kernel_launch(void* const* d_in, const int* in_sizes, int n_in,
                              void* d_out, int out_size, void* d_ws, size_t ws_size,
                              hipStream_t stream)
{
    const float* ee  = (const float*)d_in[0];
    const float* en  = (const float*)d_in[1];
    const float* X   = (const float*)d_in[2];
    const float* Y   = (const float*)d_in[3];
    const float* wW1 = (const float*)d_in[4];
    const float* wb1 = (const float*)d_in[5];
    const float* wW2 = (const float*)d_in[6];
    const float* wb2 = (const float*)d_in[7];
    const float* hW  = (const float*)d_in[8];
    const float* hb  = (const float*)d_in[9];
    const float* gW  = (const float*)d_in[10];
    const float* gb  = (const float*)d_in[11];
    float* xout = (float*)d_out;

    // workspace carve (byte offsets, all 16B-aligned)
    char* ws = (char*)d_ws;
    float*          h   = (float*)(ws);                         // 8,388,608 B
    unsigned short* zb  = (unsigned short*)(ws + 8388608);      // 12,582,912 B
    float*          h0  = (float*)(ws + 8388608 + 12582912);    // 256 B
    short*          w1B = (short*)(ws + 20971520 + 256);        // 27,648 B
    short*          w2B = w1B + (size_t)27 * 512;               // 73,728 B
    short*          gB  = w2B + (size_t)72 * 512;               // 147,456 B
    short*          hB  = gB  + (size_t)144 * 512;              // 32,768 B
    float*          gbs = (float*)(hB + (size_t)32 * 512);      // 1,536 B

    prep_kernel<<<276, 256, 0, stream>>>(wW1, wb1, wW2, wb2, gW, hW, gb,
                                         w1B, w2B, gB, hB, gbs);
    h0_kernel<<<1, 64, 0, stream>>>(X, hW, hb, h0);

    // layer 0
    edge_kernel<<<8192, 256, 0, stream>>>(ee, en, Y, w1B, wb1, w2B, h, h0, zb, 0, 0);
    fuse_kernel<<<512, 256, 0, stream>>>(zb, gB, gbs, X, hB, hb, xout, h, 0, 1, 1);
    // layer 1
    edge_kernel<<<8192, 256, 0, stream>>>(ee, en, Y, w1B, wb1, w2B, h, h0, zb, 1, 1);
    fuse_kernel<<<512, 256, 0, stream>>>(zb, gB, gbs, X, hB, hb, xout, h, 1, 0, 1);
    // layer 2
    edge_kernel<<<8192, 256, 0, stream>>>(ee, en, Y, w1B, wb1, w2B, h, h0, zb, 2, 1);
    fuse_kernel<<<512, 256, 0, stream>>>(zb, gB, gbs, X, hB, hb, xout, h, 2, 0, 0);
}